// Round 1
// baseline (167.431 us; speedup 1.0000x reference)
//
#include <hip/hip_runtime.h>

// ---------------------------------------------------------------------------
// AttentionHead: out = softmax(mask(q k^T / sqrt(384))) v, q/k/v = x @ W{q,k,v}
// B=256, T=256, C=384, H=64.
// FUSED: one block per batch, 1024 thr (16 waves = 4/SIMD), 1 block/CU.
//   Phase 1: wave w projects token-tile w (16 tokens). W chunk (12 KB) staged
//            in double-buffered LDS (ONE relaxed barrier per kc: lgkmcnt-only
//            drain + raw s_barrier, so x/W global prefetch loads stay in
//            flight across the barrier -- T4 counted-vmcnt mechanism; a full
//            __syncthreads would emit s_waitcnt vmcnt(0) and empty the HBM
//            pipe 12x per block). x read with depth-2 register prefetch.
//            k/v stored frag-linear in LDS; q stays in REGISTERS (converted
//            C->B-operand layout by the verified 8-shuffle transform;
//            phase-2 tile w == phase-1 tile w).
//   Phase 2: wave w owns q-tile w. QK^T + exp + PV merged in one loop
//            (no max pass; logits bounded). S^T = MFMA(A=K,B=Q) so the P
//            C->A transform is 8 register shuffles per 32-chunk. Independent
//            MFMA pair + vector add (no C-dependency chain).
// Frag-linear: lane l's 16-B fragment of chunk c at base + c*1024 + l*16.
//   Wt_sw : [kc:12][nt:12][lane:64][j:8] (nt<4: q-feats x 1/sqrt(384), <8: k, else v)
//   k LDS: [tile:16][kc:2][lane:64][j:8]   v LDS: [kc:8][nt:4][lane:64][j:8]
// ---------------------------------------------------------------------------

typedef short s16x8 __attribute__((ext_vector_type(8)));   // 8 x bf16 raw bits
typedef float f32x4 __attribute__((ext_vector_type(4)));
typedef float f32x2 __attribute__((ext_vector_type(2)));
typedef unsigned u32x4 __attribute__((ext_vector_type(4)));
typedef __bf16 bf16x2t __attribute__((ext_vector_type(2)));

#define MFMA16(a, b, c) __builtin_amdgcn_mfma_f32_16x16x32_bf16((a), (b), (c), 0, 0, 0)

__device__ __forceinline__ unsigned short f2bf(float f) {
  return __builtin_bit_cast(unsigned short, (__bf16)f);     // RNE
}
__device__ __forceinline__ unsigned cvt2(float a, float b) { // 2 f32 -> packed bf16x2
  f32x2 t; t[0] = a; t[1] = b;
  bf16x2t r = __builtin_convertvector(t, bf16x2t);
  return __builtin_bit_cast(unsigned, r);
}
__device__ __forceinline__ s16x8 cvt8(float4 a, float4 b) { // 8 f32 -> bf16 frag
  u32x4 u;
  u[0] = cvt2(a.x, a.y); u[1] = cvt2(a.z, a.w);
  u[2] = cvt2(b.x, b.y); u[3] = cvt2(b.z, b.w);
  return __builtin_bit_cast(s16x8, u);
}
// C-layout tile pair (packed bf16x2) -> A/B-operand fragment (verified R5-R7)
__device__ __forceinline__ s16x8 asm_frag(uint2 t0, uint2 t1, int laneA, bool hi) {
  unsigned r0a = __shfl(t0.x, laneA),      r0b = __shfl(t0.y, laneA);
  unsigned r0c = __shfl(t0.x, laneA + 16), r0d = __shfl(t0.y, laneA + 16);
  unsigned r1a = __shfl(t1.x, laneA),      r1b = __shfl(t1.y, laneA);
  unsigned r1c = __shfl(t1.x, laneA + 16), r1d = __shfl(t1.y, laneA + 16);
  u32x4 u;
  u[0] = hi ? r1a : r0a; u[1] = hi ? r1b : r0b;
  u[2] = hi ? r1c : r0c; u[3] = hi ? r1d : r0d;
  return __builtin_bit_cast(s16x8, u);
}

// ---------------------------------------------------------------------------
// Kernel 0: build frag-linear Wt_sw from fp32 Wq/Wk/Wv.
// ---------------------------------------------------------------------------
__global__ __launch_bounds__(256) void wcvt(
    const float* __restrict__ Wq, const float* __restrict__ Wk,
    const float* __restrict__ Wv, unsigned short* __restrict__ Wt_sw) {
  int idx = blockIdx.x * 256 + threadIdx.x;   // 73728 = 12*12*64*8
  int j = idx & 7;
  int c = idx >> 3;
  int n15 = c & 15;
  int q4 = (c >> 4) & 3;
  int g = c >> 6;
  int nt = g % 12;
  int kc = g / 12;
  int n = nt * 16 + n15;                      // output feature 0..191
  int kk = kc * 32 + q4 * 8 + j;              // reduction index 0..383
  const float* src = (n < 64) ? Wq : (n < 128) ? Wk : Wv;
  float v = src[kk * 64 + (n & 63)];
  if (n < 64) v *= 0.05103103630798287f;      // fold 1/sqrt(384) into Wq
  Wt_sw[idx] = f2bf(v);
}

// ---------------------------------------------------------------------------
// Fused kernel: one block per batch, 16 waves.
// ---------------------------------------------------------------------------
__global__ __launch_bounds__(1024, 4) void fused_attn(
    const float* __restrict__ x, const unsigned short* __restrict__ Wt_sw,
    float* __restrict__ out) {
  __shared__ __align__(16) unsigned short k_l[16384];   // 32 KB
  __shared__ __align__(16) unsigned short v_l[16384];   // 32 KB (V^T frags)
  __shared__ __align__(16) unsigned short w_l[12288];   // 24 KB: W chunk dbuf
  const int b = blockIdx.x;
  const int tid = threadIdx.x;
  const int wv = tid >> 6;                // 0..15 = token tile = q-tile
  const int lane = tid & 63;
  const int n15 = lane & 15;
  const int q4 = lane >> 4;

  // ======================= Phase 1: QKV =======================
  f32x4 acc[12];
#pragma unroll
  for (int i = 0; i < 12; ++i) acc[i] = (f32x4){0.f, 0.f, 0.f, 0.f};

  const float* xp = x + ((long)b * 256 + wv * 16 + n15) * 384 + q4 * 8;
  float4 f0a = *reinterpret_cast<const float4*>(xp);
  float4 f0b = *reinterpret_cast<const float4*>(xp + 4);
  float4 f1a = *reinterpret_cast<const float4*>(xp + 32);
  float4 f1b = *reinterpret_cast<const float4*>(xp + 36);

  const uint4* Wv4 = reinterpret_cast<const uint4*>(Wt_sw);
  uint4* wl4 = reinterpret_cast<uint4*>(w_l);
  uint4 wreg;
  if (tid < 768) wreg = Wv4[tid];

  for (int kc = 0; kc < 12; ++kc) {
    if (tid < 768) wl4[(kc & 1) * 768 + tid] = wreg;
    // Relaxed barrier: drain LDS only (the ds_write above must be visible
    // block-wide); global x/W prefetch loads stay in flight across the
    // barrier. sched_barrier(0) fences pin the store below / the wbuf
    // ds_reads above from migrating across (ERRATA #18 discipline).
    __builtin_amdgcn_sched_barrier(0);
    asm volatile("s_waitcnt lgkmcnt(0)" ::: "memory");
    __builtin_amdgcn_s_barrier();
    __builtin_amdgcn_sched_barrier(0);
    if (kc < 11 && tid < 768) wreg = Wv4[(kc + 1) * 768 + tid];
    const int nkc = (kc < 10) ? kc + 2 : 11;        // depth-2 x prefetch
    float4 pa = *reinterpret_cast<const float4*>(xp + nkc * 32);
    float4 pb = *reinterpret_cast<const float4*>(xp + nkc * 32 + 4);

    s16x8 xa = cvt8(f0a, f0b);
    const unsigned short* wbuf = w_l + (kc & 1) * 6144;
#pragma unroll
    for (int nt = 0; nt < 12; ++nt) {
      s16x8 wf = *reinterpret_cast<const s16x8*>(&wbuf[nt * 512 + lane * 8]);
      if (nt < 8) acc[nt] = MFMA16(wf, xa, acc[nt]);  // q/k: features on m
      else        acc[nt] = MFMA16(xa, wf, acc[nt]);  // v: tokens on m
    }
    f0a = f1a; f0b = f1b; f1a = pa; f1b = pb;
  }

  // q (acc[0..3]) -> packed C-layout pairs, stays in registers
  uint2 pkq[4];
#pragma unroll
  for (int mt = 0; mt < 4; ++mt) {
    pkq[mt].x = cvt2(acc[mt][0], acc[mt][1]);
    pkq[mt].y = cvt2(acc[mt][2], acc[mt][3]);
  }
  // k/v -> frag-linear LDS (8-B packed stores)
#pragma unroll
  for (int mt = 0; mt < 4; ++mt) {
    const int off = ((wv * 2 + (mt >> 1)) * 64 + (2 * (mt & 1) + (q4 >> 1)) * 16 + n15) * 8
                    + (q4 & 1) * 4;
    uint2 sk;
    sk.x = cvt2(acc[4 + mt][0], acc[4 + mt][1]);
    sk.y = cvt2(acc[4 + mt][2], acc[4 + mt][3]);
    *reinterpret_cast<uint2*>(&k_l[off]) = sk;
  }
  const int s0 = wv * 16 + q4 * 4;
#pragma unroll
  for (int nt = 0; nt < 4; ++nt) {
    const int off = (((s0 >> 5) * 4 + nt) * 64 + ((s0 >> 3) & 3) * 16 + n15) * 8 + (s0 & 7);
    uint2 sv;
    sv.x = cvt2(acc[8 + nt][0], acc[8 + nt][1]);
    sv.y = cvt2(acc[8 + nt][2], acc[8 + nt][3]);
    *reinterpret_cast<uint2*>(&v_l[off]) = sv;
  }

  // assemble q B-operand frags in registers (within-wave, pre-barrier OK)
  const int laneA = ((q4 & 1) << 5) + n15;
  const bool hi = (q4 >> 1) != 0;
  const s16x8 qf0 = asm_frag(pkq[0], pkq[1], laneA, hi);  // feats 0..31
  const s16x8 qf1 = asm_frag(pkq[2], pkq[3], laneA, hi);  // feats 32..63
  __syncthreads();   // full drain: k/v LDS writes must be globally visible

  // ======================= Phase 2: attention (tile qt = wv) ==============
  const int qt = wv;
  const f32x4 zf = (f32x4){0.f, 0.f, 0.f, 0.f};
  f32x4 O[4];
#pragma unroll
  for (int nt = 0; nt < 4; ++nt) O[nt] = zf;
  float psum = 0.f;
  const int nk = (qt + 2) >> 1;               // ceil((qt+1)/2)
#pragma unroll 8
  for (int kc = 0; kc < 8; ++kc) {
    if (kc >= nk) break;
    const int ct0 = 2 * kc;
    const bool has1 = (ct0 + 1 <= qt);        // wave-uniform
    s16x8 kf0 = *reinterpret_cast<const s16x8*>(&k_l[(ct0 * 2 + 0) * 512 + lane * 8]);
    s16x8 kf1 = *reinterpret_cast<const s16x8*>(&k_l[(ct0 * 2 + 1) * 512 + lane * 8]);
    f32x4 a0 = MFMA16(kf0, qf0, zf);          // independent pair, no C-chain
    f32x4 a1 = MFMA16(kf1, qf1, zf);
    uint2 t0, t1;
    {
      f32x4 s = a0 + a1;
      const bool diag = (ct0 == qt);
      float p[4];
#pragma unroll
      for (int e = 0; e < 4; ++e) {
        p[e] = (diag && (q4 * 4 + e > n15)) ? 0.f : __expf(s[e]);
        psum += p[e];
      }
      t0.x = cvt2(p[0], p[1]); t0.y = cvt2(p[2], p[3]);
    }
    if (has1) {
      const int ct1 = ct0 + 1;
      s16x8 kg0 = *reinterpret_cast<const s16x8*>(&k_l[(ct1 * 2 + 0) * 512 + lane * 8]);
      s16x8 kg1 = *reinterpret_cast<const s16x8*>(&k_l[(ct1 * 2 + 1) * 512 + lane * 8]);
      f32x4 b0 = MFMA16(kg0, qf0, zf);
      f32x4 b1 = MFMA16(kg1, qf1, zf);
      f32x4 s = b0 + b1;
      const bool diag = (ct1 == qt);
      float p[4];
#pragma unroll
      for (int e = 0; e < 4; ++e) {
        p[e] = (diag && (q4 * 4 + e > n15)) ? 0.f : __expf(s[e]);
        psum += p[e];
      }
      t1.x = cvt2(p[0], p[1]); t1.y = cvt2(p[2], p[3]);
    } else {
      t1 = make_uint2(0u, 0u);
    }
    s16x8 pf = asm_frag(t0, t1, laneA, hi);   // A[m=n15][s=32kc+q4*8+j]
#pragma unroll
    for (int nt = 0; nt < 4; ++nt) {
      s16x8 vf = *reinterpret_cast<const s16x8*>(&v_l[(kc * 4 + nt) * 512 + lane * 8]);
      O[nt] = MFMA16(pf, vf, O[nt]);
    }
  }
  psum += __shfl_xor(psum, 16);
  psum += __shfl_xor(psum, 32);
  const float rn_col = 1.0f / psum;           // row sum for m = n15
  float rnm[4];
#pragma unroll
  for (int e = 0; e < 4; ++e) rnm[e] = __shfl(rn_col, q4 * 4 + e);
#pragma unroll
  for (int nt = 0; nt < 4; ++nt)
#pragma unroll
    for (int e = 0; e < 4; ++e)
      out[(size_t)(b * 256 + qt * 16 + q4 * 4 + e) * 64 + nt * 16 + n15] = O[nt][e] * rnm[e];
}

extern "C" void kernel_launch(void* const* d_in, const int* in_sizes, int n_in,
                              void* d_out, int out_size, void* d_ws, size_t ws_size,
                              hipStream_t stream) {
  const float* x  = (const float*)d_in[0];
  const float* Wq = (const float*)d_in[1];
  const float* Wk = (const float*)d_in[2];
  const float* Wv = (const float*)d_in[3];
  float* out = (float*)d_out;

  unsigned short* Wt_sw = (unsigned short*)d_ws;  // 73728 bf16 = 144 KB

  wcvt<<<288, 256, 0, stream>>>(Wq, Wk, Wv, Wt_sw);
  fused_attn<<<256, 1024, 0, stream>>>(x, Wt_sw, out);
}

// Round 2
// 166.449 us; speedup vs baseline: 1.0059x; 1.0059x over previous
//
#include <hip/hip_runtime.h>

// ---------------------------------------------------------------------------
// AttentionHead: out = softmax(mask(q k^T / sqrt(384))) v, q/k/v = x @ W{q,k,v}
// B=256, T=256, C=384, H=64.
// FUSED: one block per batch, 1024 thr (16 waves = 4/SIMD), 1 block/CU.
//   Phase 1: ALL of W (144 KB bf16, frag-linear) is staged into LDS ONCE at
//            kernel entry; the 12-kc projection loop then runs with ZERO
//            barriers -- waves fully decoupled, ds_read/MFMA/x-prefetch
//            software-pipelined freely by the compiler. x read with depth-2
//            register prefetch. Wave w projects token-tile tt(w).
//   Alias:   after the post-loop barrier, the first 64 KB of the W region are
//            REUSED for k (32 KB) + v (32 KB). Own-wave safety is by dataflow
//            (W reads feed MFMAs that feed the packed k/v values); cross-wave
//            safety is the post-loop __syncthreads (drains lgkmcnt).
//   Phase 2: wave w owns q-tile tt(w). QK^T + exp + PV merged in one loop
//            (no max pass; logits bounded). S^T = MFMA(A=K,B=Q) so the P
//            C->A transform is 8 register shuffles per 32-chunk.
//   Balance: tt maps SIMD s to tiles {s, 7-s, 8+s, 15-s} so per-SIMD causal
//            phase-2 work is equal (18 kc-units per SIMD vs 16..20 for id map).
// Frag-linear: lane l's 16-B fragment of chunk c at base + c*1024 + l*16.
//   W LDS : [kc:12][nt:12][lane:64][j:8] (nt<4: q-feats x 1/sqrt(384), <8: k, else v)
//   k LDS: [tile:16][kc:2][lane:64][j:8]   v LDS: [kc:8][nt:4][lane:64][j:8]
// ---------------------------------------------------------------------------

typedef short s16x8 __attribute__((ext_vector_type(8)));   // 8 x bf16 raw bits
typedef float f32x4 __attribute__((ext_vector_type(4)));
typedef float f32x2 __attribute__((ext_vector_type(2)));
typedef unsigned u32x4 __attribute__((ext_vector_type(4)));
typedef __bf16 bf16x2t __attribute__((ext_vector_type(2)));

#define MFMA16(a, b, c) __builtin_amdgcn_mfma_f32_16x16x32_bf16((a), (b), (c), 0, 0, 0)

__device__ __forceinline__ unsigned short f2bf(float f) {
  return __builtin_bit_cast(unsigned short, (__bf16)f);     // RNE
}
__device__ __forceinline__ unsigned cvt2(float a, float b) { // 2 f32 -> packed bf16x2
  f32x2 t; t[0] = a; t[1] = b;
  bf16x2t r = __builtin_convertvector(t, bf16x2t);
  return __builtin_bit_cast(unsigned, r);
}
__device__ __forceinline__ s16x8 cvt8(float4 a, float4 b) { // 8 f32 -> bf16 frag
  u32x4 u;
  u[0] = cvt2(a.x, a.y); u[1] = cvt2(a.z, a.w);
  u[2] = cvt2(b.x, b.y); u[3] = cvt2(b.z, b.w);
  return __builtin_bit_cast(s16x8, u);
}
// C-layout tile pair (packed bf16x2) -> A/B-operand fragment (verified R5-R7)
__device__ __forceinline__ s16x8 asm_frag(uint2 t0, uint2 t1, int laneA, bool hi) {
  unsigned r0a = __shfl(t0.x, laneA),      r0b = __shfl(t0.y, laneA);
  unsigned r0c = __shfl(t0.x, laneA + 16), r0d = __shfl(t0.y, laneA + 16);
  unsigned r1a = __shfl(t1.x, laneA),      r1b = __shfl(t1.y, laneA);
  unsigned r1c = __shfl(t1.x, laneA + 16), r1d = __shfl(t1.y, laneA + 16);
  u32x4 u;
  u[0] = hi ? r1a : r0a; u[1] = hi ? r1b : r0b;
  u[2] = hi ? r1c : r0c; u[3] = hi ? r1d : r0d;
  return __builtin_bit_cast(s16x8, u);
}

// ---------------------------------------------------------------------------
// Kernel 0: build frag-linear Wt_sw from fp32 Wq/Wk/Wv.
// ---------------------------------------------------------------------------
__global__ __launch_bounds__(256) void wcvt(
    const float* __restrict__ Wq, const float* __restrict__ Wk,
    const float* __restrict__ Wv, unsigned short* __restrict__ Wt_sw) {
  int idx = blockIdx.x * 256 + threadIdx.x;   // 73728 = 12*12*64*8
  int j = idx & 7;
  int c = idx >> 3;
  int n15 = c & 15;
  int q4 = (c >> 4) & 3;
  int g = c >> 6;
  int nt = g % 12;
  int kc = g / 12;
  int n = nt * 16 + n15;                      // output feature 0..191
  int kk = kc * 32 + q4 * 8 + j;              // reduction index 0..383
  const float* src = (n < 64) ? Wq : (n < 128) ? Wk : Wv;
  float v = src[kk * 64 + (n & 63)];
  if (n < 64) v *= 0.05103103630798287f;      // fold 1/sqrt(384) into Wq
  Wt_sw[idx] = f2bf(v);
}

// ---------------------------------------------------------------------------
// Fused kernel: one block per batch, 16 waves.
// ---------------------------------------------------------------------------
__global__ __launch_bounds__(1024, 4) void fused_attn(
    const float* __restrict__ x, const unsigned short* __restrict__ Wt_sw,
    float* __restrict__ out) {
  // 144 KB: holds all 12 W chunks during phase 1; first 64 KB reused for k/v.
  __shared__ __align__(16) unsigned short smem[73728];
  unsigned short* const k_l = smem;            // 32 KB (aliases W chunks 0..2)
  unsigned short* const v_l = smem + 16384;    // 32 KB (aliases W chunks 2..5)
  const int b = blockIdx.x;
  const int tid = threadIdx.x;
  const int wv = tid >> 6;                // 0..15
  const int lane = tid & 63;
  const int n15 = lane & 15;
  const int q4 = lane >> 4;
  // Balanced tile map: SIMD s = wv&3 owns tiles {s, 7-s, 8+s, 15-s}.
  const int tt = ((wv >> 3) & 1) * 8 + (((wv >> 2) & 1) ? 7 - (wv & 3) : (wv & 3));

  // ======================= Phase 1: QKV =======================
  f32x4 acc[12];
#pragma unroll
  for (int i = 0; i < 12; ++i) acc[i] = (f32x4){0.f, 0.f, 0.f, 0.f};

  const float* xp = x + ((long)b * 256 + tt * 16 + n15) * 384 + q4 * 8;
  float4 f0a = *reinterpret_cast<const float4*>(xp);       // issue x prefetch
  float4 f0b = *reinterpret_cast<const float4*>(xp + 4);   // before W staging
  float4 f1a = *reinterpret_cast<const float4*>(xp + 32);
  float4 f1b = *reinterpret_cast<const float4*>(xp + 36);

  // Stage ALL of W (144 KB, L2-hot) into LDS: linear copy, 9 uint4/thread.
  const uint4* Wv4 = reinterpret_cast<const uint4*>(Wt_sw);
  uint4* wl4 = reinterpret_cast<uint4*>(smem);
#pragma unroll
  for (int i = 0; i < 9; ++i) wl4[i * 1024 + tid] = Wv4[i * 1024 + tid];
  __syncthreads();                        // W visible block-wide

  // Barrier-free projection loop: waves fully decoupled.
  for (int kc = 0; kc < 12; ++kc) {
    const int nkc = (kc < 10) ? kc + 2 : 11;        // depth-2 x prefetch
    float4 pa = *reinterpret_cast<const float4*>(xp + nkc * 32);
    float4 pb = *reinterpret_cast<const float4*>(xp + nkc * 32 + 4);

    s16x8 xa = cvt8(f0a, f0b);
    const unsigned short* wbuf = smem + kc * 6144;
#pragma unroll
    for (int nt = 0; nt < 12; ++nt) {
      s16x8 wf = *reinterpret_cast<const s16x8*>(&wbuf[nt * 512 + lane * 8]);
      if (nt < 8) acc[nt] = MFMA16(wf, xa, acc[nt]);  // q/k: features on m
      else        acc[nt] = MFMA16(xa, wf, acc[nt]);  // v: tokens on m
    }
    f0a = f1a; f0b = f1b; f1a = pa; f1b = pb;
  }

  // Pack q/k/v into registers BEFORE the barrier (register-only work).
  uint2 pkq[4];
#pragma unroll
  for (int mt = 0; mt < 4; ++mt) {
    pkq[mt].x = cvt2(acc[mt][0], acc[mt][1]);
    pkq[mt].y = cvt2(acc[mt][2], acc[mt][3]);
  }
  uint2 sk[4], sv[4];
  int koff[4], voff[4];
#pragma unroll
  for (int mt = 0; mt < 4; ++mt) {
    koff[mt] = ((tt * 2 + (mt >> 1)) * 64 + (2 * (mt & 1) + (q4 >> 1)) * 16 + n15) * 8
               + (q4 & 1) * 4;
    sk[mt].x = cvt2(acc[4 + mt][0], acc[4 + mt][1]);
    sk[mt].y = cvt2(acc[4 + mt][2], acc[4 + mt][3]);
  }
  const int s0 = tt * 16 + q4 * 4;
#pragma unroll
  for (int nt = 0; nt < 4; ++nt) {
    voff[nt] = (((s0 >> 5) * 4 + nt) * 64 + ((s0 >> 3) & 3) * 16 + n15) * 8 + (s0 & 7);
    sv[nt].x = cvt2(acc[8 + nt][0], acc[8 + nt][1]);
    sv[nt].y = cvt2(acc[8 + nt][2], acc[8 + nt][3]);
  }
  // assemble q B-operand frags in registers (within-wave shuffles)
  const int laneA = ((q4 & 1) << 5) + n15;
  const bool hi = (q4 >> 1) != 0;
  const s16x8 qf0 = asm_frag(pkq[0], pkq[1], laneA, hi);  // feats 0..31
  const s16x8 qf1 = asm_frag(pkq[2], pkq[3], laneA, hi);  // feats 32..63

  __syncthreads();   // all W reads drained -> safe to overwrite W region
#pragma unroll
  for (int mt = 0; mt < 4; ++mt)
    *reinterpret_cast<uint2*>(&k_l[koff[mt]]) = sk[mt];
#pragma unroll
  for (int nt = 0; nt < 4; ++nt)
    *reinterpret_cast<uint2*>(&v_l[voff[nt]]) = sv[nt];
  __syncthreads();   // k/v visible block-wide

  // ======================= Phase 2: attention (tile qt = tt) ==============
  const int qt = tt;
  const f32x4 zf = (f32x4){0.f, 0.f, 0.f, 0.f};
  f32x4 O[4];
#pragma unroll
  for (int nt = 0; nt < 4; ++nt) O[nt] = zf;
  float psum = 0.f;
  const int nk = (qt + 2) >> 1;               // ceil((qt+1)/2)
#pragma unroll 8
  for (int kc = 0; kc < 8; ++kc) {
    if (kc >= nk) break;
    const int ct0 = 2 * kc;
    const bool has1 = (ct0 + 1 <= qt);        // wave-uniform
    s16x8 kf0 = *reinterpret_cast<const s16x8*>(&k_l[(ct0 * 2 + 0) * 512 + lane * 8]);
    s16x8 kf1 = *reinterpret_cast<const s16x8*>(&k_l[(ct0 * 2 + 1) * 512 + lane * 8]);
    f32x4 a0 = MFMA16(kf0, qf0, zf);          // independent pair, no C-chain
    f32x4 a1 = MFMA16(kf1, qf1, zf);
    uint2 t0, t1;
    {
      f32x4 s = a0 + a1;
      const bool diag = (ct0 == qt);
      float p[4];
#pragma unroll
      for (int e = 0; e < 4; ++e) {
        p[e] = (diag && (q4 * 4 + e > n15)) ? 0.f : __expf(s[e]);
        psum += p[e];
      }
      t0.x = cvt2(p[0], p[1]); t0.y = cvt2(p[2], p[3]);
    }
    if (has1) {
      const int ct1 = ct0 + 1;
      s16x8 kg0 = *reinterpret_cast<const s16x8*>(&k_l[(ct1 * 2 + 0) * 512 + lane * 8]);
      s16x8 kg1 = *reinterpret_cast<const s16x8*>(&k_l[(ct1 * 2 + 1) * 512 + lane * 8]);
      f32x4 b0 = MFMA16(kg0, qf0, zf);
      f32x4 b1 = MFMA16(kg1, qf1, zf);
      f32x4 s = b0 + b1;
      const bool diag = (ct1 == qt);
      float p[4];
#pragma unroll
      for (int e = 0; e < 4; ++e) {
        p[e] = (diag && (q4 * 4 + e > n15)) ? 0.f : __expf(s[e]);
        psum += p[e];
      }
      t1.x = cvt2(p[0], p[1]); t1.y = cvt2(p[2], p[3]);
    } else {
      t1 = make_uint2(0u, 0u);
    }
    s16x8 pf = asm_frag(t0, t1, laneA, hi);   // A[m=n15][s=32kc+q4*8+j]
#pragma unroll
    for (int nt = 0; nt < 4; ++nt) {
      s16x8 vf = *reinterpret_cast<const s16x8*>(&v_l[(kc * 4 + nt) * 512 + lane * 8]);
      O[nt] = MFMA16(pf, vf, O[nt]);
    }
  }
  psum += __shfl_xor(psum, 16);
  psum += __shfl_xor(psum, 32);
  const float rn_col = 1.0f / psum;           // row sum for m = n15
  float rnm[4];
#pragma unroll
  for (int e = 0; e < 4; ++e) rnm[e] = __shfl(rn_col, q4 * 4 + e);
#pragma unroll
  for (int nt = 0; nt < 4; ++nt)
#pragma unroll
    for (int e = 0; e < 4; ++e)
      out[(size_t)(b * 256 + qt * 16 + q4 * 4 + e) * 64 + nt * 16 + n15] = O[nt][e] * rnm[e];
}

extern "C" void kernel_launch(void* const* d_in, const int* in_sizes, int n_in,
                              void* d_out, int out_size, void* d_ws, size_t ws_size,
                              hipStream_t stream) {
  const float* x  = (const float*)d_in[0];
  const float* Wq = (const float*)d_in[1];
  const float* Wk = (const float*)d_in[2];
  const float* Wv = (const float*)d_in[3];
  float* out = (float*)d_out;

  unsigned short* Wt_sw = (unsigned short*)d_ws;  // 73728 bf16 = 144 KB

  wcvt<<<288, 256, 0, stream>>>(Wq, Wk, Wv, Wt_sw);
  fused_attn<<<256, 1024, 0, stream>>>(x, Wt_sw, out);
}